// Round 13
// baseline (244.620 us; speedup 1.0000x reference)
//
#include <hip/hip_runtime.h>
#include <hip/hip_bf16.h>

#define B_SZ    2
#define S_LEN   2048
#define D_MODEL 2048
#define N_HEADS 16
#define D_HEAD  128
#define L_RANK  64
#define M_ROWS  (B_SZ * S_LEN)   // 4096
#define KD      2048             // GEMM K
#define NT      (KD / 32)        // 64 K-steps (128^2 kernels)
#define NTK     (KD / 64)        // 32 K-tiles (8-phase kernels)

typedef short          bf16x8 __attribute__((ext_vector_type(8)));
typedef float          f32x4  __attribute__((ext_vector_type(4)));
typedef float          f32x16 __attribute__((ext_vector_type(16)));
typedef unsigned short us4v   __attribute__((ext_vector_type(4)));
typedef unsigned short us8v   __attribute__((ext_vector_type(8)));
typedef unsigned int   u32x4  __attribute__((ext_vector_type(4)));

// log2(e) / sqrt(128), folded into the Q projection epilogue
#define SCALE_Q 0.127517432f

static __device__ __forceinline__ unsigned short f2bf(float f) {
    unsigned int u = __float_as_uint(f);
    u += 0x7FFFu + ((u >> 16) & 1u);      // RNE; inputs finite
    return (unsigned short)(u >> 16);
}
static __device__ __forceinline__ float bf2f(unsigned short u) {
    return __uint_as_float(((unsigned int)u) << 16);
}

static __device__ __forceinline__ void gload16(const void* g, void* l) {
    __builtin_amdgcn_global_load_lds(
        (const __attribute__((address_space(1))) unsigned int*)g,
        (__attribute__((address_space(3))) unsigned int*)l, 16, 0, 0);
}

// compiler-invisible LDS read (defeats alias-driven auto vmcnt waits);
// MUST be followed by explicit lgkmcnt(0) + sched_barrier(0) before use.
static __device__ __forceinline__ bf16x8 ds_read128(const unsigned short* p) {
    bf16x8 r;
    unsigned int a = (unsigned int)(size_t)
        (const __attribute__((address_space(3))) unsigned short*)p;
    asm volatile("ds_read_b128 %0, %1" : "=&v"(r) : "v"(a));
    return r;
}

static __device__ __forceinline__ float exp2_hw(float x) {
    float r; asm("v_exp_f32 %0, %1" : "=v"(r) : "v"(x)); return r;
}
static __device__ __forceinline__ unsigned int cvtpk_bf16(float a, float b) {
    unsigned int r; asm("v_cvt_pk_bf16_f32 %0, %1, %2" : "=v"(r) : "v"(a), "v"(b)); return r;
}

// ---------------------------------------------------------------------------
// Fused prep (unchanged)
// ---------------------------------------------------------------------------
__global__ __launch_bounds__(256) void prep_kernel(
    const float* __restrict__ q_in, const float* __restrict__ k_in,
    const float* __restrict__ v_in,
    const float* __restrict__ Wq, const float* __restrict__ Wlk,
    const float* __restrict__ Wlv, const float* __restrict__ Wo,
    const float* __restrict__ Wkr, const float* __restrict__ Wvr,
    unsigned short* __restrict__ q_o, unsigned short* __restrict__ k_o,
    unsigned short* __restrict__ v_o,
    unsigned short* __restrict__ WqT, unsigned short* __restrict__ WlkT,
    unsigned short* __restrict__ WlvT, unsigned short* __restrict__ WoT,
    unsigned short* __restrict__ WkrT, unsigned short* __restrict__ WvrT)
{
    __shared__ float tl[64][69];
    const int bid = blockIdx.x, tid = threadIdx.x;

    if (bid < 12288) {
        const int z = bid >> 12;
        const float* in = z == 0 ? q_in : (z == 1 ? k_in : v_in);
        unsigned short* out = z == 0 ? q_o : (z == 1 ? k_o : v_o);
        size_t i = ((size_t)(bid & 4095) * 256 + tid) * 8;
        float4 a = *(const float4*)&in[i];
        float4 b = *(const float4*)&in[i + 4];
        us8v o = { f2bf(a.x), f2bf(a.y), f2bf(a.z), f2bf(a.w),
                   f2bf(b.x), f2bf(b.y), f2bf(b.z), f2bf(b.w) };
        *(us8v*)&out[i] = o;
    } else if (bid < 16384) {
        const int t = bid - 12288;
        const int z = t >> 10;               // 0:Wq 1:Wlk 2:Wlv 3:Wo
        const int y = (t & 1023) >> 5, x = t & 31;
        const int Nz = (z == 1 || z == 2) ? 1024 : 2048;
        if (x * 64 >= Nz) return;
        const float* W = z == 0 ? Wq : (z == 1 ? Wlk : (z == 2 ? Wlv : Wo));
        unsigned short* WT = z == 0 ? WqT : (z == 1 ? WlkT : (z == 2 ? WlvT : WoT));
        const int k0 = y * 64, n0 = x * 64;
        #pragma unroll
        for (int c = 0; c < 4; ++c) {
            int idx = c * 256 + tid;
            int r = idx >> 4, c4 = (idx & 15) * 4;
            float4 v = *(const float4*)&W[(size_t)(k0 + r) * Nz + n0 + c4];
            tl[r][c4] = v.x; tl[r][c4 + 1] = v.y; tl[r][c4 + 2] = v.z; tl[r][c4 + 3] = v.w;
        }
        __syncthreads();
        #pragma unroll
        for (int c = 0; c < 2; ++c) {
            int idx = c * 256 + tid;
            int nr = idx >> 3, s = idx & 7;
            us8v o;
            #pragma unroll
            for (int j = 0; j < 8; ++j) o[j] = f2bf(tl[s * 8 + j][nr]);
            *(us8v*)&WT[(size_t)(n0 + nr) * KD + k0 + s * 8] = o;
        }
    } else {
        #pragma unroll 1
        for (int t2 = 0; t2 < 2; ++t2) {
            const float* W = t2 ? Wvr : Wkr;
            unsigned short* WT = t2 ? WvrT : WkrT;
            for (int i = 0; i < 32; ++i) {
                int e = i * 256 + tid;
                int d = e >> 6, l = e & 63;
                WT[d * 64 + l] = f2bf(W[l * 128 + d]);
            }
        }
    }
}

// ---------------------------------------------------------------------------
// Stage-1 batched GEMM, 256x256, 8-phase gated (unchanged — proven).
// ---------------------------------------------------------------------------
__global__ __launch_bounds__(512) void stage1_8p_kernel(
    const unsigned short* __restrict__ Aq, const unsigned short* __restrict__ Ak,
    const unsigned short* __restrict__ Av,
    const unsigned short* __restrict__ WqT, const unsigned short* __restrict__ WlkT,
    const unsigned short* __restrict__ WlvT,
    const float* __restrict__ bq, const float* __restrict__ blk,
    const float* __restrict__ blv,
    unsigned short* __restrict__ q_bf, unsigned short* __restrict__ lat_k,
    unsigned short* __restrict__ lat_v)
{
    __shared__ unsigned short Al[2][2][256 * 32];
    __shared__ unsigned short Bl[2][2][256 * 32];

    const int bid = blockIdx.x;
    const int swz = (bid & 7) * 32 + (bid >> 3);   // 256 blocks, bijective
    int z, rem, row0, col0, Nz;
    if (swz < 128)      { z = 0; rem = swz;       row0 = (rem >> 3) * 256; col0 = (rem & 7) * 256; Nz = 2048; }
    else if (swz < 192) { z = 1; rem = swz - 128; row0 = (rem >> 2) * 256; col0 = (rem & 3) * 256; Nz = 1024; }
    else                { z = 2; rem = swz - 192; row0 = (rem >> 2) * 256; col0 = (rem & 3) * 256; Nz = 1024; }

    const unsigned short* A    = z == 0 ? Aq  : (z == 1 ? Ak   : Av);
    const unsigned short* Bt   = z == 0 ? WqT : (z == 1 ? WlkT : WlvT);
    const float*          bias = z == 0 ? bq  : (z == 1 ? blk  : blv);
    unsigned short*       C    = z == 0 ? q_bf : (z == 1 ? lat_k : lat_v);

    const int tid = threadIdx.x;
    const int lane = tid & 63, wid = tid >> 6;
    const int lr = lane & 15, lg = lane >> 4;
    const int wm = wid >> 2, wn = wid & 3;

    const int lin0 = tid, lin1 = 512 + tid;
    const int rS0 = lin0 >> 2, rS1 = lin1 >> 2;
    const int cS0 = (lin0 & 3) ^ ((rS0 >> 1) & 3);
    const int cS1 = (lin1 & 3) ^ ((rS1 >> 1) & 3);
    const unsigned short* aS0 = A  + (size_t)(row0 + rS0) * KD + cS0 * 8;
    const unsigned short* aS1 = A  + (size_t)(row0 + rS1) * KD + cS1 * 8;
    const unsigned short* bS0 = Bt + (size_t)(col0 + rS0) * KD + cS0 * 8;
    const unsigned short* bS1 = Bt + (size_t)(col0 + rS1) * KD + cS1 * 8;
    const int d0 = lin0 * 8, d1 = lin1 * 8;

    int aoff[8], boff[4];
    #pragma unroll
    for (int m = 0; m < 8; ++m) {
        int row = wm * 128 + m * 16 + lr;
        aoff[m] = row * 32 + ((lg ^ ((row >> 1) & 3)) * 8);
    }
    #pragma unroll
    for (int n = 0; n < 4; ++n) {
        int row = wn * 64 + n * 16 + lr;
        boff[n] = row * 32 + ((lg ^ ((row >> 1) & 3)) * 8);
    }

    f32x4 acc[8][4];
    #pragma unroll
    for (int m = 0; m < 8; ++m)
        #pragma unroll
        for (int n = 0; n < 4; ++n) acc[m][n] = (f32x4){0.f, 0.f, 0.f, 0.f};

#define STAGE_A(buf, kh, kt) do { \
        gload16(aS0 + (size_t)(kt) * 64 + (kh) * 32, &Al[buf][kh][d0]); \
        gload16(aS1 + (size_t)(kt) * 64 + (kh) * 32, &Al[buf][kh][d1]); } while (0)
#define STAGE_B(buf, kh, kt) do { \
        gload16(bS0 + (size_t)(kt) * 64 + (kh) * 32, &Bl[buf][kh][d0]); \
        gload16(bS1 + (size_t)(kt) * 64 + (kh) * 32, &Bl[buf][kh][d1]); } while (0)

    STAGE_A(0, 0, 0); STAGE_B(0, 0, 0); STAGE_A(0, 1, 0); STAGE_B(0, 1, 0);

    #pragma unroll 1
    for (int t = 0; t < NTK; ++t) {
        const int cur = t & 1, nxt = cur ^ 1;
        const bool more = (t + 1 < NTK);

        asm volatile("s_waitcnt vmcnt(4)" ::: "memory");
        __builtin_amdgcn_s_barrier();
        asm volatile("" ::: "memory");

        bf16x8 af[8], bf0, bf1;
        if (more) STAGE_A(nxt, 0, t + 1);
        #pragma unroll
        for (int m = 0; m < 8; ++m) af[m] = ds_read128(&Al[cur][0][aoff[m]]);
        bf0 = ds_read128(&Bl[cur][0][boff[0]]);
        bf1 = ds_read128(&Bl[cur][0][boff[1]]);
        asm volatile("s_waitcnt lgkmcnt(0)" ::: "memory");
        __builtin_amdgcn_sched_barrier(0);
        __builtin_amdgcn_s_setprio(1);
        #pragma unroll
        for (int m = 0; m < 8; ++m) {
            acc[m][0] = __builtin_amdgcn_mfma_f32_16x16x32_bf16(af[m], bf0, acc[m][0], 0, 0, 0);
            acc[m][1] = __builtin_amdgcn_mfma_f32_16x16x32_bf16(af[m], bf1, acc[m][1], 0, 0, 0);
        }
        __builtin_amdgcn_s_setprio(0);

        if (more) STAGE_B(nxt, 0, t + 1);
        bf0 = ds_read128(&Bl[cur][0][boff[2]]);
        bf1 = ds_read128(&Bl[cur][0][boff[3]]);
        asm volatile("s_waitcnt lgkmcnt(0)" ::: "memory");
        __builtin_amdgcn_sched_barrier(0);
        __builtin_amdgcn_s_setprio(1);
        #pragma unroll
        for (int m = 0; m < 8; ++m) {
            acc[m][2] = __builtin_amdgcn_mfma_f32_16x16x32_bf16(af[m], bf0, acc[m][2], 0, 0, 0);
            acc[m][3] = __builtin_amdgcn_mfma_f32_16x16x32_bf16(af[m], bf1, acc[m][3], 0, 0, 0);
        }
        __builtin_amdgcn_s_setprio(0);

        if (more) asm volatile("s_waitcnt vmcnt(4)" ::: "memory");
        else      asm volatile("s_waitcnt vmcnt(0)" ::: "memory");
        __builtin_amdgcn_s_barrier();
        asm volatile("" ::: "memory");

        if (more) STAGE_A(nxt, 1, t + 1);
        #pragma unroll
        for (int m = 0; m < 8; ++m) af[m] = ds_read128(&Al[cur][1][aoff[m]]);
        bf0 = ds_read128(&Bl[cur][1][boff[0]]);
        bf1 = ds_read128(&Bl[cur][1][boff[1]]);
        asm volatile("s_waitcnt lgkmcnt(0)" ::: "memory");
        __builtin_amdgcn_sched_barrier(0);
        __builtin_amdgcn_s_setprio(1);
        #pragma unroll
        for (int m = 0; m < 8; ++m) {
            acc[m][0] = __builtin_amdgcn_mfma_f32_16x16x32_bf16(af[m], bf0, acc[m][0], 0, 0, 0);
            acc[m][1] = __builtin_amdgcn_mfma_f32_16x16x32_bf16(af[m], bf1, acc[m][1], 0, 0, 0);
        }
        __builtin_amdgcn_s_setprio(0);

        if (more) STAGE_B(nxt, 1, t + 1);
        bf0 = ds_read128(&Bl[cur][1][boff[2]]);
        bf1 = ds_read128(&Bl[cur][1][boff[3]]);
        asm volatile("s_waitcnt lgkmcnt(0)" ::: "memory");
        __builtin_amdgcn_sched_barrier(0);
        __builtin_amdgcn_s_setprio(1);
        #pragma unroll
        for (int m = 0; m < 8; ++m) {
            acc[m][2] = __builtin_amdgcn_mfma_f32_16x16x32_bf16(af[m], bf0, acc[m][2], 0, 0, 0);
            acc[m][3] = __builtin_amdgcn_mfma_f32_16x16x32_bf16(af[m], bf1, acc[m][3], 0, 0, 0);
        }
        __builtin_amdgcn_s_setprio(0);
    }
#undef STAGE_A
#undef STAGE_B

    float bv[4];
    #pragma unroll
    for (int n = 0; n < 4; ++n) bv[n] = bias[col0 + wn * 64 + n * 16 + lr];
    const float omul = (z == 0) ? SCALE_Q : 1.0f;

    #pragma unroll
    for (int m = 0; m < 8; ++m) {
        #pragma unroll
        for (int n = 0; n < 4; ++n) {
            const int col = col0 + wn * 64 + n * 16 + lr;
            const int rowb = row0 + wm * 128 + m * 16 + lg * 4;
            #pragma unroll
            for (int j = 0; j < 4; ++j)
                C[(size_t)(rowb + j) * Nz + col] = f2bf((acc[m][n][j] + bv[n]) * omul);
        }
    }
}

// ---------------------------------------------------------------------------
// Output GEMM, 8-phase gated (unchanged — proven).
// ---------------------------------------------------------------------------
__global__ __launch_bounds__(512) void out_gemm8p_kernel(
    const unsigned short* __restrict__ A,
    const unsigned short* __restrict__ Bt,
    const float* __restrict__ bias,
    float* __restrict__ C)
{
    __shared__ unsigned short Al[2][2][128 * 32];   // 32 KB
    __shared__ unsigned short Bl[2][2][256 * 32];   // 64 KB

    const int bid = blockIdx.x;
    const int swz = (bid & 7) * 32 + (bid >> 3);    // 256 blocks, bijective
    const int row0 = (swz >> 3) * 128, col0 = (swz & 7) * 256;

    const int tid = threadIdx.x;
    const int lane = tid & 63, wid = tid >> 6;
    const int lr = lane & 15, lg = lane >> 4;
    const int wm = wid >> 2, wn = wid & 3;

    const int rA = tid >> 2;
    const int cA = (tid & 3) ^ ((rA >> 1) & 3);
    const unsigned short* aS = A + (size_t)(row0 + rA) * KD + cA * 8;
    const int dA = tid * 8;
    const int lin0 = tid, lin1 = 512 + tid;
    const int rB0 = lin0 >> 2, rB1 = lin1 >> 2;
    const int cB0 = (lin0 & 3) ^ ((rB0 >> 1) & 3);
    const int cB1 = (lin1 & 3) ^ ((rB1 >> 1) & 3);
    const unsigned short* bS0 = Bt + (size_t)(col0 + rB0) * KD + cB0 * 8;
    const unsigned short* bS1 = Bt + (size_t)(col0 + rB1) * KD + cB1 * 8;
    const int dB0 = lin0 * 8, dB1 = lin1 * 8;

    int aoff[4], boff[4];
    #pragma unroll
    for (int m = 0; m < 4; ++m) {
        int row = wm * 64 + m * 16 + lr;
        aoff[m] = row * 32 + ((lg ^ ((row >> 1) & 3)) * 8);
    }
    #pragma unroll
    for (int n = 0; n < 4; ++n) {
        int row = wn * 64 + n * 16 + lr;
        boff[n] = row * 32 + ((lg ^ ((row >> 1) & 3)) * 8);
    }

    f32x4 acc[4][4];
    #pragma unroll
    for (int m = 0; m < 4; ++m)
        #pragma unroll
        for (int n = 0; n < 4; ++n) acc[m][n] = (f32x4){0.f, 0.f, 0.f, 0.f};

#define STAGE_A(buf, kh, kt) \
        gload16(aS + (size_t)(kt) * 64 + (kh) * 32, &Al[buf][kh][dA])
#define STAGE_B(buf, kh, kt) do { \
        gload16(bS0 + (size_t)(kt) * 64 + (kh) * 32, &Bl[buf][kh][dB0]); \
        gload16(bS1 + (size_t)(kt) * 64 + (kh) * 32, &Bl[buf][kh][dB1]); } while (0)

    STAGE_A(0, 0, 0); STAGE_B(0, 0, 0); STAGE_A(0, 1, 0); STAGE_B(0, 1, 0);

    #pragma unroll 1
    for (int t = 0; t < NTK; ++t) {
        const int cur = t & 1, nxt = cur ^ 1;
        const bool more = (t + 1 < NTK);

        asm volatile("s_waitcnt vmcnt(3)" ::: "memory");
        __builtin_amdgcn_s_barrier();
        asm volatile("" ::: "memory");

        bf16x8 af[4], bf0, bf1;
        if (more) STAGE_A(nxt, 0, t + 1);
        #pragma unroll
        for (int m = 0; m < 4; ++m) af[m] = ds_read128(&Al[cur][0][aoff[m]]);
        bf0 = ds_read128(&Bl[cur][0][boff[0]]);
        bf1 = ds_read128(&Bl[cur][0][boff[1]]);
        asm volatile("s_waitcnt lgkmcnt(0)" ::: "memory");
        __builtin_amdgcn_sched_barrier(0);
        __builtin_amdgcn_s_setprio(1);
        #pragma unroll
        for (int m = 0; m < 4; ++m) {
            acc[m][0] = __builtin_amdgcn_mfma_f32_16x16x32_bf16(af[m], bf0, acc[m][0], 0, 0, 0);
            acc[m][1] = __builtin_amdgcn_mfma_f32_16x16x32_bf16(af[m], bf1, acc[m][1], 0, 0, 0);
        }
        __builtin_amdgcn_s_setprio(0);

        if (more) STAGE_B(nxt, 0, t + 1);
        bf0 = ds_read128(&Bl[cur][0][boff[2]]);
        bf1 = ds_read128(&Bl[cur][0][boff[3]]);
        asm volatile("s_waitcnt lgkmcnt(0)" ::: "memory");
        __builtin_amdgcn_sched_barrier(0);
        __builtin_amdgcn_s_setprio(1);
        #pragma unroll
        for (int m = 0; m < 4; ++m) {
            acc[m][2] = __builtin_amdgcn_mfma_f32_16x16x32_bf16(af[m], bf0, acc[m][2], 0, 0, 0);
            acc[m][3] = __builtin_amdgcn_mfma_f32_16x16x32_bf16(af[m], bf1, acc[m][3], 0, 0, 0);
        }
        __builtin_amdgcn_s_setprio(0);

        if (more) asm volatile("s_waitcnt vmcnt(3)" ::: "memory");
        else      asm volatile("s_waitcnt vmcnt(0)" ::: "memory");
        __builtin_amdgcn_s_barrier();
        asm volatile("" ::: "memory");

        if (more) STAGE_A(nxt, 1, t + 1);
        #pragma unroll
        for (int m = 0; m < 4; ++m) af[m] = ds_read128(&Al[cur][1][aoff[m]]);
        bf0 = ds_read128(&Bl[cur][1][boff[0]]);
        bf1 = ds_read128(&Bl[cur][1][boff[1]]);
        asm volatile("s_waitcnt lgkmcnt(0)" ::: "memory");
        __builtin_amdgcn_sched_barrier(0);
        __builtin_amdgcn_s_setprio(1);
        #pragma unroll
        for (int m = 0; m < 4; ++m) {
            acc[m][0] = __builtin_amdgcn_mfma_f32_16x16x32_bf16(af[m], bf0, acc[m][0], 0, 0, 0);
            acc[m][1] = __builtin_amdgcn_mfma_f32_16x16x32_bf16(af[m], bf1, acc[m][1], 0, 0, 0);
        }
        __builtin_amdgcn_s_setprio(0);

        if (more) STAGE_B(nxt, 1, t + 1);
        bf0 = ds_read128(&Bl[cur][1][boff[2]]);
        bf1 = ds_read128(&Bl[cur][1][boff[3]]);
        asm volatile("s_waitcnt lgkmcnt(0)" ::: "memory");
        __builtin_amdgcn_sched_barrier(0);
        __builtin_amdgcn_s_setprio(1);
        #pragma unroll
        for (int m = 0; m < 4; ++m) {
            acc[m][2] = __builtin_amdgcn_mfma_f32_16x16x32_bf16(af[m], bf0, acc[m][2], 0, 0, 0);
            acc[m][3] = __builtin_amdgcn_mfma_f32_16x16x32_bf16(af[m], bf1, acc[m][3], 0, 0, 0);
        }
        __builtin_amdgcn_s_setprio(0);
    }
#undef STAGE_A
#undef STAGE_B

    float bv[4];
    #pragma unroll
    for (int n = 0; n < 4; ++n) bv[n] = bias[col0 + wn * 64 + n * 16 + lr];
    #pragma unroll
    for (int m = 0; m < 4; ++m)
        #pragma unroll
        for (int n = 0; n < 4; ++n) {
            const int col = col0 + wn * 64 + n * 16 + lr;
            const int rowb = row0 + wm * 64 + m * 16 + lg * 4;
            #pragma unroll
            for (int j = 0; j < 4; ++j)
                C[(size_t)(rowb + j) * D_MODEL + col] = acc[m][n][j] + bv[n];
        }
}

// ---------------------------------------------------------------------------
// Stage-2 recon (unchanged)
// ---------------------------------------------------------------------------
__global__ __launch_bounds__(256) void recon_kernel(
    const unsigned short* __restrict__ lat_k, const unsigned short* __restrict__ lat_v,
    const unsigned short* __restrict__ WkrT, const unsigned short* __restrict__ WvrT,
    const float* __restrict__ bkr, const float* __restrict__ bvr,
    unsigned short* __restrict__ k_bf, unsigned short* __restrict__ v_t)
{
    __shared__ unsigned short Alds[128 * 64];
    __shared__ unsigned short Blds[128 * 64];

    const int flat = blockIdx.x;
    const int swz = (flat & 7) * 128 + (flat >> 3);   // 1024 = 8*128
    const int z = swz >> 9;
    const int rem = swz & 511;
    const int h = rem >> 5;
    const int r0 = (rem & 31) * 128;

    const unsigned short* lat = z ? lat_v : lat_k;
    const unsigned short* WT  = z ? WvrT : WkrT;
    const float* bias = z ? bvr : bkr;

    const int tid = threadIdx.x;
    const int lane = tid & 63, wid = tid >> 6;
    const int lr = lane & 15, lg = lane >> 4;
    const int wm = wid >> 1, wn = wid & 1;

    #pragma unroll
    for (int c = 0; c < 4; ++c) {
        int e = c * 256 + tid;
        int row = e >> 3, pc = e & 7;
        gload16(lat + (size_t)(r0 + row) * 1024 + h * 64 + ((pc ^ (row & 7)) * 8),
                Alds + e * 8);
    }
    #pragma unroll
    for (int c = 0; c < 4; ++c) {
        int e = c * 256 + tid;
        int d = e >> 3, pc = e & 7;
        gload16(WT + (size_t)d * 64 + ((pc ^ (d & 7)) * 8), Blds + e * 8);
    }
    __syncthreads();

    f32x4 acc[4][4];
    #pragma unroll
    for (int m = 0; m < 4; ++m)
        #pragma unroll
        for (int n = 0; n < 4; ++n) acc[m][n] = (f32x4){0.f, 0.f, 0.f, 0.f};

    #pragma unroll
    for (int ks = 0; ks < 2; ++ks) {
        bf16x8 af[4], bfv[4];
        #pragma unroll
        for (int m = 0; m < 4; ++m) {
            int row = wm * 64 + m * 16 + lr;
            af[m] = *(const bf16x8*)&Alds[row * 64 + (((ks * 4 + lg) ^ (row & 7)) * 8)];
        }
        #pragma unroll
        for (int n = 0; n < 4; ++n) {
            int row = wn * 64 + n * 16 + lr;
            bfv[n] = *(const bf16x8*)&Blds[row * 64 + (((ks * 4 + lg) ^ (row & 7)) * 8)];
        }
        #pragma unroll
        for (int m = 0; m < 4; ++m)
            #pragma unroll
            for (int n = 0; n < 4; ++n)
                acc[m][n] = __builtin_amdgcn_mfma_f32_16x16x32_bf16(af[m], bfv[n], acc[m][n], 0, 0, 0);
    }

    const int b = r0 >> 11;
    float bv[4];
    #pragma unroll
    for (int n = 0; n < 4; ++n) bv[n] = bias[wn * 64 + n * 16 + lr];

    #pragma unroll
    for (int m = 0; m < 4; ++m) {
        #pragma unroll
        for (int n = 0; n < 4; ++n) {
            const int d = wn * 64 + n * 16 + lr;
            const int rowb = r0 + wm * 64 + m * 16 + lg * 4;
            if (z == 0) {
                #pragma unroll
                for (int j = 0; j < 4; ++j)
                    k_bf[(size_t)(rowb + j) * D_MODEL + h * D_HEAD + d] =
                        f2bf(acc[m][n][j] + bv[n]);
            } else {
                us4v o = { f2bf(acc[m][n][0] + bv[n]), f2bf(acc[m][n][1] + bv[n]),
                           f2bf(acc[m][n][2] + bv[n]), f2bf(acc[m][n][3] + bv[n]) };
                *(us4v*)&v_t[((size_t)(b * 16 + h) * 128 + d) * 2048 + (rowb & 2047)] = o;
            }
        }
    }
}

// ---------------------------------------------------------------------------
// Split-KV causal flash: each block = (bh, qt, chunk) computing a PARTIAL
// over <=8 KV tiles; writes unnormalized O (bf16) + per-row (m,l) (f32).
// nchunks(qt) = (qt>>2)+1; 40 slots per bh, 1280 blocks total.
// SLOT LAYOUT: slot = bh*40 + s  (must match merge_kernel exactly).
// ---------------------------------------------------------------------------
static __device__ __forceinline__ void flash_stage(
    const unsigned short* __restrict__ kgh,
    const unsigned short* __restrict__ vtb,
    unsigned short* Kl, unsigned short* Vl, int kv0, int tid)
{
    #pragma unroll
    for (int c = 0; c < 4; ++c) {
        int idx = c * 256 + tid;
        int r = idx >> 4, ch = idx & 15;
        gload16(kgh + (size_t)(kv0 + r) * D_MODEL + ((ch ^ (r & 7)) * 8), Kl + idx * 8);
    }
    #pragma unroll
    for (int c = 0; c < 4; ++c) {
        int idx = c * 256 + tid;
        int d = idx >> 3, ch = idx & 7;
        gload16(vtb + (size_t)d * S_LEN + kv0 + ((ch ^ (d & 7)) * 8), Vl + idx * 8);
    }
}

__global__ __launch_bounds__(256, 2) void flash_pk_kernel(
    const unsigned short* __restrict__ Q,
    const unsigned short* __restrict__ Kg,
    const unsigned short* __restrict__ Vt,
    unsigned short* __restrict__ Op,     // [1280][128][128] bf16 unnormalized
    float* __restrict__ mlbuf)           // [1280][128][2] f32 {m, l}
{
    __shared__ unsigned short Klds[2][64 * 128];
    __shared__ unsigned short Vlds[2][128 * 64];

    const int tid = threadIdx.x;
    const int lane = tid & 63, wid = tid >> 6;
    const int lc = lane & 31, hi = lane >> 5;

    const int flat = blockIdx.x;         // 1280
    const int bh = flat & 31;
    const int s = flat >> 5;             // slot within bh, [0,40)
    const int g = (s < 4) ? 0 : (s < 12) ? 1 : (s < 24) ? 2 : 3;
    const int sp = s - 2 * g * (g + 1);
    const int qt = 4 * g + sp / (g + 1);
    const int ck = sp % (g + 1);
    const int slot = bh * 40 + s;        // FIXED: must match merge layout

    const int b = bh >> 4, h = bh & 15;
    const size_t base = (size_t)b * S_LEN * D_MODEL;
    const unsigned short* kgh = Kg + base + h * D_HEAD;
    const unsigned short* vtb = Vt + (size_t)bh * D_HEAD * S_LEN;

    const int nt = 2 * qt + 2;
    const int t0 = ck * 8;
    const int ntl = min(8, nt - t0);

    const int q0w = qt * 128 + wid * 32;
    const int qcol = q0w + lc;

    bf16x8 qf[8];
    #pragma unroll
    for (int dc = 0; dc < 8; ++dc)
        qf[dc] = *(const bf16x8*)&Q[base + (size_t)qcol * D_MODEL + h * D_HEAD + dc * 16 + hi * 8];

    f32x16 o_acc[4];
    #pragma unroll
    for (int dt = 0; dt < 4; ++dt)
        #pragma unroll
        for (int r = 0; r < 16; ++r) o_acc[dt][r] = 0.f;
    float m_r = -3e38f, l_r = 0.f;

    const int kxor = lc & 7;

    int koff[16];
    #pragma unroll
    for (int dc = 0; dc < 8; ++dc) {
        koff[2 * dc]     = lc * 128 + (((dc * 2 + hi) ^ kxor) * 8);
        koff[2 * dc + 1] = (32 + lc) * 128 + (((dc * 2 + hi) ^ kxor) * 8);
    }

    flash_stage(kgh, vtb, Klds[0], Vlds[0], t0 * 64, tid);

    #pragma unroll 1
    for (int tl = 0; tl < ntl; ++tl) {
        const int bb = tl & 1;
        const int tg = t0 + tl;
        const int kv0 = tg * 64;

        asm volatile("s_waitcnt vmcnt(0)" ::: "memory");
        __builtin_amdgcn_s_barrier();
        asm volatile("" ::: "memory");

        if (tl + 1 < ntl)
            flash_stage(kgh, vtb, Klds[bb ^ 1], Vlds[bb ^ 1], (tg + 1) * 64, tid);

        const unsigned short* Kb = Klds[bb];
        const unsigned short* Vb = Vlds[bb];

        f32x16 s0a, s0b, s1a, s1b;
        #pragma unroll
        for (int r = 0; r < 16; ++r) { s0a[r] = 0.f; s0b[r] = 0.f; s1a[r] = 0.f; s1b[r] = 0.f; }

        bf16x8 kf[8];
        #pragma unroll
        for (int i = 0; i < 8; ++i) kf[i] = ds_read128(&Kb[koff[i]]);
        asm volatile("s_waitcnt lgkmcnt(0)" ::: "memory");
        __builtin_amdgcn_sched_barrier(0);
        __builtin_amdgcn_s_setprio(1);
        #pragma unroll
        for (int dc = 0; dc < 4; ++dc) {
            s0a = __builtin_amdgcn_mfma_f32_32x32x16_bf16(kf[2 * dc],     qf[dc], s0a, 0, 0, 0);
            s1a = __builtin_amdgcn_mfma_f32_32x32x16_bf16(kf[2 * dc + 1], qf[dc], s1a, 0, 0, 0);
        }
        __builtin_amdgcn_s_setprio(0);

        #pragma unroll
        for (int i = 0; i < 8; ++i) kf[i] = ds_read128(&Kb[koff[8 + i]]);
        asm volatile("s_waitcnt lgkmcnt(0)" ::: "memory");
        __builtin_amdgcn_sched_barrier(0);
        __builtin_amdgcn_s_setprio(1);
        #pragma unroll
        for (int dc = 0; dc < 4; ++dc) {
            s0b = __builtin_amdgcn_mfma_f32_32x32x16_bf16(kf[2 * dc],     qf[dc + 4], s0b, 0, 0, 0);
            s1b = __builtin_amdgcn_mfma_f32_32x32x16_bf16(kf[2 * dc + 1], qf[dc + 4], s1b, 0, 0, 0);
        }
        __builtin_amdgcn_s_setprio(0);

        f32x16 s0 = s0a + s0b;
        f32x16 s1 = s1a + s1b;

        if (tg >= nt - 2) {
            #pragma unroll
            for (int r = 0; r < 16; ++r) {
                int krow = (r & 3) + 8 * (r >> 2) + 4 * hi;
                if (kv0 + krow > qcol)      s0[r] = -3e38f;
                if (kv0 + 32 + krow > qcol) s1[r] = -3e38f;
            }
        }

        float mt[8];
        #pragma unroll
        for (int i = 0; i < 8; ++i)
            mt[i] = fmaxf(fmaxf(s0[2 * i], s0[2 * i + 1]), fmaxf(s1[2 * i], s1[2 * i + 1]));
        float mA = fmaxf(fmaxf(mt[0], mt[1]), fmaxf(mt[2], mt[3]));
        float mB = fmaxf(fmaxf(mt[4], mt[5]), fmaxf(mt[6], mt[7]));
        float sm = fmaxf(mA, mB);
        sm = fmaxf(sm, __shfl_xor(sm, 32));

        if (__any(sm > m_r + 11.5f)) {
            float mnew = fmaxf(m_r, sm);
            float alpha = exp2_hw(m_r - mnew);
            l_r *= alpha;
            m_r = mnew;
            #pragma unroll
            for (int r = 0; r < 16; ++r) {
                float av = __shfl(alpha, (r & 3) + 8 * (r >> 2) + 4 * hi);
                #pragma unroll
                for (int dt = 0; dt < 4; ++dt) o_acc[dt][r] *= av;
            }
        }

        #pragma unroll
        for (int r = 0; r < 16; ++r) {
            s0[r] = exp2_hw(s0[r] - m_r);
            s1[r] = exp2_hw(s1[r] - m_r);
        }
        float st[8];
        #pragma unroll
        for (int i = 0; i < 8; ++i)
            st[i] = (s0[2 * i] + s0[2 * i + 1]) + (s1[2 * i] + s1[2 * i + 1]);
        l_r += ((st[0] + st[1]) + (st[2] + st[3])) + ((st[4] + st[5]) + (st[6] + st[7]));

        #pragma unroll
        for (int t32 = 0; t32 < 2; ++t32) {
            const f32x16& sv = t32 ? s1 : s0;
            unsigned int c0[4], c1[4];
            #pragma unroll
            for (int gq = 0; gq < 4; ++gq) {
                c0[gq] = cvtpk_bf16(sv[4 * gq],     sv[4 * gq + 1]);
                c1[gq] = cvtpk_bf16(sv[4 * gq + 2], sv[4 * gq + 3]);
            }
            bf16x8 pf[2];
            #pragma unroll
            for (int kt = 0; kt < 2; ++kt) {
                unsigned int sel0 = hi ? c0[2 * kt] : c0[2 * kt + 1];
                unsigned int sel1 = hi ? c1[2 * kt] : c1[2 * kt + 1];
                unsigned int o0 = (unsigned int)__shfl_xor((int)sel0, 32);
                unsigned int o1 = (unsigned int)__shfl_xor((int)sel1, 32);
                u32x4 uu;
                uu.x = hi ? o0 : c0[2 * kt];
                uu.y = hi ? o1 : c1[2 * kt];
                uu.z = hi ? c0[2 * kt + 1] : o0;
                uu.w = hi ? c1[2 * kt + 1] : o1;
                pf[kt] = __builtin_bit_cast(bf16x8, uu);
            }
            bf16x8 vf[8];
            #pragma unroll
            for (int kt = 0; kt < 2; ++kt)
                #pragma unroll
                for (int dt = 0; dt < 4; ++dt)
                    vf[kt * 4 + dt] = ds_read128(
                        &Vb[(dt * 32 + lc) * 64 + (((t32 * 4 + kt * 2 + hi) ^ kxor) * 8)]);
            asm volatile("s_waitcnt lgkmcnt(0)" ::: "memory");
            __builtin_amdgcn_sched_barrier(0);
            __builtin_amdgcn_s_setprio(1);
            #pragma unroll
            for (int kt = 0; kt < 2; ++kt)
                #pragma unroll
                for (int dt = 0; dt < 4; ++dt)
                    o_acc[dt] = __builtin_amdgcn_mfma_f32_32x32x16_bf16(
                        pf[kt], vf[kt * 4 + dt], o_acc[dt], 0, 0, 0);
            __builtin_amdgcn_s_setprio(0);
        }
    }

    // ---- write partial: unnormalized O (bf16) + per-row m,l (f32) ----
    float lt = l_r + __shfl_xor(l_r, 32);
    if (hi == 0) {
        mlbuf[((size_t)slot * 128 + wid * 32 + lc) * 2]     = m_r;
        mlbuf[((size_t)slot * 128 + wid * 32 + lc) * 2 + 1] = lt;
    }
    #pragma unroll
    for (int r = 0; r < 16; ++r) {
        int qrow = (r & 3) + 8 * (r >> 2) + 4 * hi;
        #pragma unroll
        for (int dt = 0; dt < 4; ++dt)
            Op[(size_t)slot * 16384 + (wid * 32 + qrow) * 128 + dt * 32 + lc] =
                f2bf(o_acc[dt][r]);
    }
}

// ---------------------------------------------------------------------------
// Merge partials: for each (bh, qt), combine nch=(qt>>2)+1 chunks.
// grid 512 (bh,qt), 256 threads: thread = (row, 64-col half).
// ---------------------------------------------------------------------------
__global__ __launch_bounds__(256) void merge_kernel(
    const unsigned short* __restrict__ Op, const float* __restrict__ mlbuf,
    unsigned short* __restrict__ ao)
{
    const int bid = blockIdx.x;          // 512
    const int bh = bid & 31, qt = bid >> 5;
    const int b = bh >> 4, h = bh & 15;
    const int g = qt >> 2, nch = g + 1;
    const int slot0 = bh * 40 + 2 * g * (g + 1) + (qt & 3) * nch;

    const int tid = threadIdx.x;
    const int row = tid >> 1, colh = (tid & 1) * 64;

    float m_c[4], l_c[4], w[4];
    float mstar = -3e38f;
    #pragma unroll
    for (int cc = 0; cc < 4; ++cc) {
        if (cc < nch) {
            m_c[cc] = mlbuf[((size_t)(slot0 + cc) * 128 + row) * 2];
            l_c[cc] = mlbuf[((size_t)(slot0 + cc) * 128 + row) * 2 + 1];
            mstar = fmaxf(mstar, m_c[cc]);
        }
    }
    float lstar = 0.f;
    #pragma unroll
    for (int cc = 0; cc < 4; ++cc) {
        if (cc < nch) {
            w[cc] = exp2_hw(m_c[cc] - mstar);
            lstar += w[cc] * l_c[cc];
        }
    }
    const float inv = 1.0f / lstar;

    float acc[64];
    #pragma unroll
    for (int j = 0; j < 64; ++j) acc[j] = 0.f;
    #pragma unroll
    for (int cc = 0; cc < 4; ++cc) {
        if (cc < nch) {
            const unsigned short* src = Op + (size_t)(slot0 + cc) * 16384 + row * 128 + colh;
            const float wc = w[cc];
            #pragma unroll
            for (int v = 0; v < 8; ++v) {
                us8v x = *(const us8v*)&src[v * 8];
                #pragma unroll
                for (int j = 0; j < 8; ++j) acc[v * 8 + j] += wc * bf2f(x[j]);
            }
        }
    }
    unsigned short* dst = ao + (size_t)(b * S_LEN + qt * 128 + row) * D_MODEL + h * D_HEAD + colh;
    #pragma unroll
    for (int v = 0; v < 8; ++v) {
        us8v o;
        #pragma unroll
        for (int j = 0; j < 8; ++j) o[j] = f2bf(acc[v * 8 + j] * inv);
        *(us8v*)&dst[v * 8] = o;
    }
}

// ---------------------------------------------------------------------------
extern "C" void kernel_launch(void* const* d_in, const int* in_sizes, int n_in,
                              void* d_out, int out_size, void* d_ws, size_t ws_size,
                              hipStream_t stream)
{
    const float* queries = (const float*)d_in[0];
    const float* keys    = (const float*)d_in[1];
    const float* values  = (const float*)d_in[2];
    const float* Wq  = (const float*)d_in[3];
    const float* bq  = (const float*)d_in[4];
    const float* Wlk = (const float*)d_in[5];
    const float* blk = (const float*)d_in[6];
    const float* Wlv = (const float*)d_in[7];
    const float* blv = (const float*)d_in[8];
    const float* Wkr = (const float*)d_in[9];
    const float* bkr = (const float*)d_in[10];
    const float* Wvr = (const float*)d_in[11];
    const float* bvr = (const float*)d_in[12];
    const float* Wo  = (const float*)d_in[13];
    const float* bo  = (const float*)d_in[14];
    float* out = (float*)d_out;

    char* ws = (char*)d_ws;
    const size_t MB = 1024 * 1024;
    unsigned short* abf_q = (unsigned short*)(ws);            // 16MB; ao aliases
    unsigned short* abf_k = (unsigned short*)(ws + 16 * MB);  // 16MB
    unsigned short* abf_v = (unsigned short*)(ws + 32 * MB);
    unsigned short* q_bf  = (unsigned short*)(ws + 48 * MB);
    unsigned short* k_bf  = (unsigned short*)(ws + 64 * MB);
    unsigned short* v_t   = (unsigned short*)(ws + 80 * MB);
    unsigned short* lat_k = (unsigned short*)(ws + 96 * MB);   // 8MB
    unsigned short* lat_v = (unsigned short*)(ws + 104 * MB);  // 8MB
    unsigned short* WqT   = (unsigned short*)(ws + 112 * MB);  // 8MB
    unsigned short* WlkT  = (unsigned short*)(ws + 120 * MB);  // 4MB
    unsigned short* WlvT  = (unsigned short*)(ws + 124 * MB);  // 4MB
    unsigned short* WkrT  = (unsigned short*)(ws + 128 * MB);  // 16KB
    unsigned short* WvrT  = WkrT + 128 * 64;
    unsigned short* WoT   = (unsigned short*)(ws + 129 * MB);  // 8MB
    unsigned short* Op    = (unsigned short*)(ws + 138 * MB);  // 40MB partial O
    float*          mlb   = (float*)(ws + 179 * MB);           // 1.3MB m,l
    unsigned short* ao    = abf_q;   // dead after stage1

    prep_kernel<<<16385, 256, 0, stream>>>(
        queries, keys, values, Wq, Wlk, Wlv, Wo, Wkr, Wvr,
        abf_q, abf_k, abf_v, WqT, WlkT, WlvT, WoT, WkrT, WvrT);

    stage1_8p_kernel<<<256, 512, 0, stream>>>(
        abf_q, abf_k, abf_v, WqT, WlkT, WlvT, bq, blk, blv,
        q_bf, lat_k, lat_v);

    recon_kernel<<<1024, 256, 0, stream>>>(
        lat_k, lat_v, WkrT, WvrT, bkr, bvr, k_bf, v_t);

    flash_pk_kernel<<<1280, 256, 0, stream>>>(q_bf, k_bf, v_t, Op, mlb);

    merge_kernel<<<512, 256, 0, stream>>>(Op, mlb, ao);

    out_gemm8p_kernel<<<256, 512, 0, stream>>>(ao, WoT, bo, out);
}

// Round 14
// 226.807 us; speedup vs baseline: 1.0785x; 1.0785x over previous
//
#include <hip/hip_runtime.h>
#include <hip/hip_bf16.h>

#define B_SZ    2
#define S_LEN   2048
#define D_MODEL 2048
#define N_HEADS 16
#define D_HEAD  128
#define L_RANK  64
#define M_ROWS  (B_SZ * S_LEN)   // 4096
#define KD      2048             // GEMM K
#define NTK     (KD / 64)        // 32 K-tiles (8-phase kernels)

typedef short          bf16x8 __attribute__((ext_vector_type(8)));
typedef float          f32x4  __attribute__((ext_vector_type(4)));
typedef float          f32x16 __attribute__((ext_vector_type(16)));
typedef unsigned short us4v   __attribute__((ext_vector_type(4)));
typedef unsigned short us8v   __attribute__((ext_vector_type(8)));
typedef unsigned int   u32x4  __attribute__((ext_vector_type(4)));

// log2(e) / sqrt(128), folded into the Q projection epilogue
#define SCALE_Q 0.127517432f

static __device__ __forceinline__ unsigned short f2bf(float f) {
    unsigned int u = __float_as_uint(f);
    u += 0x7FFFu + ((u >> 16) & 1u);      // RNE; inputs finite
    return (unsigned short)(u >> 16);
}

static __device__ __forceinline__ void gload16(const void* g, void* l) {
    __builtin_amdgcn_global_load_lds(
        (const __attribute__((address_space(1))) unsigned int*)g,
        (__attribute__((address_space(3))) unsigned int*)l, 16, 0, 0);
}

// compiler-invisible LDS read (defeats alias-driven auto vmcnt waits);
// MUST be followed by explicit lgkmcnt(0) + sched_barrier(0) before use.
static __device__ __forceinline__ bf16x8 ds_read128(const unsigned short* p) {
    bf16x8 r;
    unsigned int a = (unsigned int)(size_t)
        (const __attribute__((address_space(3))) unsigned short*)p;
    asm volatile("ds_read_b128 %0, %1" : "=&v"(r) : "v"(a));
    return r;
}

static __device__ __forceinline__ float exp2_hw(float x) {
    float r; asm("v_exp_f32 %0, %1" : "=v"(r) : "v"(x)); return r;
}
static __device__ __forceinline__ unsigned int cvtpk_bf16(float a, float b) {
    unsigned int r; asm("v_cvt_pk_bf16_f32 %0, %1, %2" : "=v"(r) : "v"(a), "v"(b)); return r;
}

// ---------------------------------------------------------------------------
// Fused prep
// ---------------------------------------------------------------------------
__global__ __launch_bounds__(256) void prep_kernel(
    const float* __restrict__ q_in, const float* __restrict__ k_in,
    const float* __restrict__ v_in,
    const float* __restrict__ Wq, const float* __restrict__ Wlk,
    const float* __restrict__ Wlv, const float* __restrict__ Wo,
    const float* __restrict__ Wkr, const float* __restrict__ Wvr,
    unsigned short* __restrict__ q_o, unsigned short* __restrict__ k_o,
    unsigned short* __restrict__ v_o,
    unsigned short* __restrict__ WqT, unsigned short* __restrict__ WlkT,
    unsigned short* __restrict__ WlvT, unsigned short* __restrict__ WoT,
    unsigned short* __restrict__ WkrT, unsigned short* __restrict__ WvrT)
{
    __shared__ float tl[64][69];
    const int bid = blockIdx.x, tid = threadIdx.x;

    if (bid < 12288) {
        const int z = bid >> 12;
        const float* in = z == 0 ? q_in : (z == 1 ? k_in : v_in);
        unsigned short* out = z == 0 ? q_o : (z == 1 ? k_o : v_o);
        size_t i = ((size_t)(bid & 4095) * 256 + tid) * 8;
        float4 a = *(const float4*)&in[i];
        float4 b = *(const float4*)&in[i + 4];
        us8v o = { f2bf(a.x), f2bf(a.y), f2bf(a.z), f2bf(a.w),
                   f2bf(b.x), f2bf(b.y), f2bf(b.z), f2bf(b.w) };
        *(us8v*)&out[i] = o;
    } else if (bid < 16384) {
        const int t = bid - 12288;
        const int z = t >> 10;               // 0:Wq 1:Wlk 2:Wlv 3:Wo
        const int y = (t & 1023) >> 5, x = t & 31;
        const int Nz = (z == 1 || z == 2) ? 1024 : 2048;
        if (x * 64 >= Nz) return;
        const float* W = z == 0 ? Wq : (z == 1 ? Wlk : (z == 2 ? Wlv : Wo));
        unsigned short* WT = z == 0 ? WqT : (z == 1 ? WlkT : (z == 2 ? WlvT : WoT));
        const int k0 = y * 64, n0 = x * 64;
        #pragma unroll
        for (int c = 0; c < 4; ++c) {
            int idx = c * 256 + tid;
            int r = idx >> 4, c4 = (idx & 15) * 4;
            float4 v = *(const float4*)&W[(size_t)(k0 + r) * Nz + n0 + c4];
            tl[r][c4] = v.x; tl[r][c4 + 1] = v.y; tl[r][c4 + 2] = v.z; tl[r][c4 + 3] = v.w;
        }
        __syncthreads();
        #pragma unroll
        for (int c = 0; c < 2; ++c) {
            int idx = c * 256 + tid;
            int nr = idx >> 3, s = idx & 7;
            us8v o;
            #pragma unroll
            for (int j = 0; j < 8; ++j) o[j] = f2bf(tl[s * 8 + j][nr]);
            *(us8v*)&WT[(size_t)(n0 + nr) * KD + k0 + s * 8] = o;
        }
    } else {
        #pragma unroll 1
        for (int t2 = 0; t2 < 2; ++t2) {
            const float* W = t2 ? Wvr : Wkr;
            unsigned short* WT = t2 ? WvrT : WkrT;
            for (int i = 0; i < 32; ++i) {
                int e = i * 256 + tid;
                int d = e >> 6, l = e & 63;
                WT[d * 64 + l] = f2bf(W[l * 128 + d]);
            }
        }
    }
}

// ---------------------------------------------------------------------------
// Stage-1 batched GEMM, 256x256, 8-phase gated (proven).
// ---------------------------------------------------------------------------
__global__ __launch_bounds__(512) void stage1_8p_kernel(
    const unsigned short* __restrict__ Aq, const unsigned short* __restrict__ Ak,
    const unsigned short* __restrict__ Av,
    const unsigned short* __restrict__ WqT, const unsigned short* __restrict__ WlkT,
    const unsigned short* __restrict__ WlvT,
    const float* __restrict__ bq, const float* __restrict__ blk,
    const float* __restrict__ blv,
    unsigned short* __restrict__ q_bf, unsigned short* __restrict__ lat_k,
    unsigned short* __restrict__ lat_v)
{
    __shared__ unsigned short Al[2][2][256 * 32];
    __shared__ unsigned short Bl[2][2][256 * 32];

    const int bid = blockIdx.x;
    const int swz = (bid & 7) * 32 + (bid >> 3);   // 256 blocks, bijective
    int z, rem, row0, col0, Nz;
    if (swz < 128)      { z = 0; rem = swz;       row0 = (rem >> 3) * 256; col0 = (rem & 7) * 256; Nz = 2048; }
    else if (swz < 192) { z = 1; rem = swz - 128; row0 = (rem >> 2) * 256; col0 = (rem & 3) * 256; Nz = 1024; }
    else                { z = 2; rem = swz - 192; row0 = (rem >> 2) * 256; col0 = (rem & 3) * 256; Nz = 1024; }

    const unsigned short* A    = z == 0 ? Aq  : (z == 1 ? Ak   : Av);
    const unsigned short* Bt   = z == 0 ? WqT : (z == 1 ? WlkT : WlvT);
    const float*          bias = z == 0 ? bq  : (z == 1 ? blk  : blv);
    unsigned short*       C    = z == 0 ? q_bf : (z == 1 ? lat_k : lat_v);

    const int tid = threadIdx.x;
    const int lane = tid & 63, wid = tid >> 6;
    const int lr = lane & 15, lg = lane >> 4;
    const int wm = wid >> 2, wn = wid & 3;

    const int lin0 = tid, lin1 = 512 + tid;
    const int rS0 = lin0 >> 2, rS1 = lin1 >> 2;
    const int cS0 = (lin0 & 3) ^ ((rS0 >> 1) & 3);
    const int cS1 = (lin1 & 3) ^ ((rS1 >> 1) & 3);
    const unsigned short* aS0 = A  + (size_t)(row0 + rS0) * KD + cS0 * 8;
    const unsigned short* aS1 = A  + (size_t)(row0 + rS1) * KD + cS1 * 8;
    const unsigned short* bS0 = Bt + (size_t)(col0 + rS0) * KD + cS0 * 8;
    const unsigned short* bS1 = Bt + (size_t)(col0 + rS1) * KD + cS1 * 8;
    const int d0 = lin0 * 8, d1 = lin1 * 8;

    int aoff[8], boff[4];
    #pragma unroll
    for (int m = 0; m < 8; ++m) {
        int row = wm * 128 + m * 16 + lr;
        aoff[m] = row * 32 + ((lg ^ ((row >> 1) & 3)) * 8);
    }
    #pragma unroll
    for (int n = 0; n < 4; ++n) {
        int row = wn * 64 + n * 16 + lr;
        boff[n] = row * 32 + ((lg ^ ((row >> 1) & 3)) * 8);
    }

    f32x4 acc[8][4];
    #pragma unroll
    for (int m = 0; m < 8; ++m)
        #pragma unroll
        for (int n = 0; n < 4; ++n) acc[m][n] = (f32x4){0.f, 0.f, 0.f, 0.f};

#define STAGE_A(buf, kh, kt) do { \
        gload16(aS0 + (size_t)(kt) * 64 + (kh) * 32, &Al[buf][kh][d0]); \
        gload16(aS1 + (size_t)(kt) * 64 + (kh) * 32, &Al[buf][kh][d1]); } while (0)
#define STAGE_B(buf, kh, kt) do { \
        gload16(bS0 + (size_t)(kt) * 64 + (kh) * 32, &Bl[buf][kh][d0]); \
        gload16(bS1 + (size_t)(kt) * 64 + (kh) * 32, &Bl[buf][kh][d1]); } while (0)

    STAGE_A(0, 0, 0); STAGE_B(0, 0, 0); STAGE_A(0, 1, 0); STAGE_B(0, 1, 0);

    #pragma unroll 1
    for (int t = 0; t < NTK; ++t) {
        const int cur = t & 1, nxt = cur ^ 1;
        const bool more = (t + 1 < NTK);

        asm volatile("s_waitcnt vmcnt(4)" ::: "memory");
        __builtin_amdgcn_s_barrier();
        asm volatile("" ::: "memory");

        bf16x8 af[8], bf0, bf1;
        if (more) STAGE_A(nxt, 0, t + 1);
        #pragma unroll
        for (int m = 0; m < 8; ++m) af[m] = ds_read128(&Al[cur][0][aoff[m]]);
        bf0 = ds_read128(&Bl[cur][0][boff[0]]);
        bf1 = ds_read128(&Bl[cur][0][boff[1]]);
        asm volatile("s_waitcnt lgkmcnt(0)" ::: "memory");
        __builtin_amdgcn_sched_barrier(0);
        __builtin_amdgcn_s_setprio(1);
        #pragma unroll
        for (int m = 0; m < 8; ++m) {
            acc[m][0] = __builtin_amdgcn_mfma_f32_16x16x32_bf16(af[m], bf0, acc[m][0], 0, 0, 0);
            acc[m][1] = __builtin_amdgcn_mfma_f32_16x16x32_bf16(af[m], bf1, acc[m][1], 0, 0, 0);
        }
        __builtin_amdgcn_s_setprio(0);

        if (more) STAGE_B(nxt, 0, t + 1);
        bf0 = ds_read128(&Bl[cur][0][boff[2]]);
        bf1 = ds_read128(&Bl[cur][0][boff[3]]);
        asm volatile("s_waitcnt lgkmcnt(0)" ::: "memory");
        __builtin_amdgcn_sched_barrier(0);
        __builtin_amdgcn_s_setprio(1);
        #pragma unroll
        for (int m = 0; m < 8; ++m) {
            acc[m][2] = __builtin_amdgcn_mfma_f32_16x16x32_bf16(af[m], bf0, acc[m][2], 0, 0, 0);
            acc[m][3] = __builtin_amdgcn_mfma_f32_16x16x32_bf16(af[m], bf1, acc[m][3], 0, 0, 0);
        }
        __builtin_amdgcn_s_setprio(0);

        if (more) asm volatile("s_waitcnt vmcnt(4)" ::: "memory");
        else      asm volatile("s_waitcnt vmcnt(0)" ::: "memory");
        __builtin_amdgcn_s_barrier();
        asm volatile("" ::: "memory");

        if (more) STAGE_A(nxt, 1, t + 1);
        #pragma unroll
        for (int m = 0; m < 8; ++m) af[m] = ds_read128(&Al[cur][1][aoff[m]]);
        bf0 = ds_read128(&Bl[cur][1][boff[0]]);
        bf1 = ds_read128(&Bl[cur][1][boff[1]]);
        asm volatile("s_waitcnt lgkmcnt(0)" ::: "memory");
        __builtin_amdgcn_sched_barrier(0);
        __builtin_amdgcn_s_setprio(1);
        #pragma unroll
        for (int m = 0; m < 8; ++m) {
            acc[m][0] = __builtin_amdgcn_mfma_f32_16x16x32_bf16(af[m], bf0, acc[m][0], 0, 0, 0);
            acc[m][1] = __builtin_amdgcn_mfma_f32_16x16x32_bf16(af[m], bf1, acc[m][1], 0, 0, 0);
        }
        __builtin_amdgcn_s_setprio(0);

        if (more) STAGE_B(nxt, 1, t + 1);
        bf0 = ds_read128(&Bl[cur][1][boff[2]]);
        bf1 = ds_read128(&Bl[cur][1][boff[3]]);
        asm volatile("s_waitcnt lgkmcnt(0)" ::: "memory");
        __builtin_amdgcn_sched_barrier(0);
        __builtin_amdgcn_s_setprio(1);
        #pragma unroll
        for (int m = 0; m < 8; ++m) {
            acc[m][2] = __builtin_amdgcn_mfma_f32_16x16x32_bf16(af[m], bf0, acc[m][2], 0, 0, 0);
            acc[m][3] = __builtin_amdgcn_mfma_f32_16x16x32_bf16(af[m], bf1, acc[m][3], 0, 0, 0);
        }
        __builtin_amdgcn_s_setprio(0);
    }
#undef STAGE_A
#undef STAGE_B

    float bv[4];
    #pragma unroll
    for (int n = 0; n < 4; ++n) bv[n] = bias[col0 + wn * 64 + n * 16 + lr];
    const float omul = (z == 0) ? SCALE_Q : 1.0f;

    #pragma unroll
    for (int m = 0; m < 8; ++m) {
        #pragma unroll
        for (int n = 0; n < 4; ++n) {
            const int col = col0 + wn * 64 + n * 16 + lr;
            const int rowb = row0 + wm * 128 + m * 16 + lg * 4;
            #pragma unroll
            for (int j = 0; j < 4; ++j)
                C[(size_t)(rowb + j) * Nz + col] = f2bf((acc[m][n][j] + bv[n]) * omul);
        }
    }
}

// ---------------------------------------------------------------------------
// Output GEMM, 8-phase gated (proven).
// ---------------------------------------------------------------------------
__global__ __launch_bounds__(512) void out_gemm8p_kernel(
    const unsigned short* __restrict__ A,
    const unsigned short* __restrict__ Bt,
    const float* __restrict__ bias,
    float* __restrict__ C)
{
    __shared__ unsigned short Al[2][2][128 * 32];   // 32 KB
    __shared__ unsigned short Bl[2][2][256 * 32];   // 64 KB

    const int bid = blockIdx.x;
    const int swz = (bid & 7) * 32 + (bid >> 3);    // 256 blocks, bijective
    const int row0 = (swz >> 3) * 128, col0 = (swz & 7) * 256;

    const int tid = threadIdx.x;
    const int lane = tid & 63, wid = tid >> 6;
    const int lr = lane & 15, lg = lane >> 4;
    const int wm = wid >> 2, wn = wid & 3;

    const int rA = tid >> 2;
    const int cA = (tid & 3) ^ ((rA >> 1) & 3);
    const unsigned short* aS = A + (size_t)(row0 + rA) * KD + cA * 8;
    const int dA = tid * 8;
    const int lin0 = tid, lin1 = 512 + tid;
    const int rB0 = lin0 >> 2, rB1 = lin1 >> 2;
    const int cB0 = (lin0 & 3) ^ ((rB0 >> 1) & 3);
    const int cB1 = (lin1 & 3) ^ ((rB1 >> 1) & 3);
    const unsigned short* bS0 = Bt + (size_t)(col0 + rB0) * KD + cB0 * 8;
    const unsigned short* bS1 = Bt + (size_t)(col0 + rB1) * KD + cB1 * 8;
    const int dB0 = lin0 * 8, dB1 = lin1 * 8;

    int aoff[4], boff[4];
    #pragma unroll
    for (int m = 0; m < 4; ++m) {
        int row = wm * 64 + m * 16 + lr;
        aoff[m] = row * 32 + ((lg ^ ((row >> 1) & 3)) * 8);
    }
    #pragma unroll
    for (int n = 0; n < 4; ++n) {
        int row = wn * 64 + n * 16 + lr;
        boff[n] = row * 32 + ((lg ^ ((row >> 1) & 3)) * 8);
    }

    f32x4 acc[4][4];
    #pragma unroll
    for (int m = 0; m < 4; ++m)
        #pragma unroll
        for (int n = 0; n < 4; ++n) acc[m][n] = (f32x4){0.f, 0.f, 0.f, 0.f};

#define STAGE_A(buf, kh, kt) \
        gload16(aS + (size_t)(kt) * 64 + (kh) * 32, &Al[buf][kh][dA])
#define STAGE_B(buf, kh, kt) do { \
        gload16(bS0 + (size_t)(kt) * 64 + (kh) * 32, &Bl[buf][kh][dB0]); \
        gload16(bS1 + (size_t)(kt) * 64 + (kh) * 32, &Bl[buf][kh][dB1]); } while (0)

    STAGE_A(0, 0, 0); STAGE_B(0, 0, 0); STAGE_A(0, 1, 0); STAGE_B(0, 1, 0);

    #pragma unroll 1
    for (int t = 0; t < NTK; ++t) {
        const int cur = t & 1, nxt = cur ^ 1;
        const bool more = (t + 1 < NTK);

        asm volatile("s_waitcnt vmcnt(3)" ::: "memory");
        __builtin_amdgcn_s_barrier();
        asm volatile("" ::: "memory");

        bf16x8 af[4], bf0, bf1;
        if (more) STAGE_A(nxt, 0, t + 1);
        #pragma unroll
        for (int m = 0; m < 4; ++m) af[m] = ds_read128(&Al[cur][0][aoff[m]]);
        bf0 = ds_read128(&Bl[cur][0][boff[0]]);
        bf1 = ds_read128(&Bl[cur][0][boff[1]]);
        asm volatile("s_waitcnt lgkmcnt(0)" ::: "memory");
        __builtin_amdgcn_sched_barrier(0);
        __builtin_amdgcn_s_setprio(1);
        #pragma unroll
        for (int m = 0; m < 4; ++m) {
            acc[m][0] = __builtin_amdgcn_mfma_f32_16x16x32_bf16(af[m], bf0, acc[m][0], 0, 0, 0);
            acc[m][1] = __builtin_amdgcn_mfma_f32_16x16x32_bf16(af[m], bf1, acc[m][1], 0, 0, 0);
        }
        __builtin_amdgcn_s_setprio(0);

        if (more) STAGE_B(nxt, 0, t + 1);
        bf0 = ds_read128(&Bl[cur][0][boff[2]]);
        bf1 = ds_read128(&Bl[cur][0][boff[3]]);
        asm volatile("s_waitcnt lgkmcnt(0)" ::: "memory");
        __builtin_amdgcn_sched_barrier(0);
        __builtin_amdgcn_s_setprio(1);
        #pragma unroll
        for (int m = 0; m < 4; ++m) {
            acc[m][2] = __builtin_amdgcn_mfma_f32_16x16x32_bf16(af[m], bf0, acc[m][2], 0, 0, 0);
            acc[m][3] = __builtin_amdgcn_mfma_f32_16x16x32_bf16(af[m], bf1, acc[m][3], 0, 0, 0);
        }
        __builtin_amdgcn_s_setprio(0);

        if (more) asm volatile("s_waitcnt vmcnt(3)" ::: "memory");
        else      asm volatile("s_waitcnt vmcnt(0)" ::: "memory");
        __builtin_amdgcn_s_barrier();
        asm volatile("" ::: "memory");

        if (more) STAGE_A(nxt, 1, t + 1);
        #pragma unroll
        for (int m = 0; m < 4; ++m) af[m] = ds_read128(&Al[cur][1][aoff[m]]);
        bf0 = ds_read128(&Bl[cur][1][boff[0]]);
        bf1 = ds_read128(&Bl[cur][1][boff[1]]);
        asm volatile("s_waitcnt lgkmcnt(0)" ::: "memory");
        __builtin_amdgcn_sched_barrier(0);
        __builtin_amdgcn_s_setprio(1);
        #pragma unroll
        for (int m = 0; m < 4; ++m) {
            acc[m][0] = __builtin_amdgcn_mfma_f32_16x16x32_bf16(af[m], bf0, acc[m][0], 0, 0, 0);
            acc[m][1] = __builtin_amdgcn_mfma_f32_16x16x32_bf16(af[m], bf1, acc[m][1], 0, 0, 0);
        }
        __builtin_amdgcn_s_setprio(0);

        if (more) STAGE_B(nxt, 1, t + 1);
        bf0 = ds_read128(&Bl[cur][1][boff[2]]);
        bf1 = ds_read128(&Bl[cur][1][boff[3]]);
        asm volatile("s_waitcnt lgkmcnt(0)" ::: "memory");
        __builtin_amdgcn_sched_barrier(0);
        __builtin_amdgcn_s_setprio(1);
        #pragma unroll
        for (int m = 0; m < 4; ++m) {
            acc[m][2] = __builtin_amdgcn_mfma_f32_16x16x32_bf16(af[m], bf0, acc[m][2], 0, 0, 0);
            acc[m][3] = __builtin_amdgcn_mfma_f32_16x16x32_bf16(af[m], bf1, acc[m][3], 0, 0, 0);
        }
        __builtin_amdgcn_s_setprio(0);
    }
#undef STAGE_A
#undef STAGE_B

    float bv[4];
    #pragma unroll
    for (int n = 0; n < 4; ++n) bv[n] = bias[col0 + wn * 64 + n * 16 + lr];
    #pragma unroll
    for (int m = 0; m < 4; ++m)
        #pragma unroll
        for (int n = 0; n < 4; ++n) {
            const int col = col0 + wn * 64 + n * 16 + lr;
            const int rowb = row0 + wm * 64 + m * 16 + lg * 4;
            #pragma unroll
            for (int j = 0; j < 4; ++j)
                C[(size_t)(rowb + j) * D_MODEL + col] = acc[m][n][j] + bv[n];
        }
}

// ---------------------------------------------------------------------------
// Stage-2 recon
// ---------------------------------------------------------------------------
__global__ __launch_bounds__(256) void recon_kernel(
    const unsigned short* __restrict__ lat_k, const unsigned short* __restrict__ lat_v,
    const unsigned short* __restrict__ WkrT, const unsigned short* __restrict__ WvrT,
    const float* __restrict__ bkr, const float* __restrict__ bvr,
    unsigned short* __restrict__ k_bf, unsigned short* __restrict__ v_t)
{
    __shared__ unsigned short Alds[128 * 64];
    __shared__ unsigned short Blds[128 * 64];

    const int flat = blockIdx.x;
    const int swz = (flat & 7) * 128 + (flat >> 3);   // 1024 = 8*128
    const int z = swz >> 9;
    const int rem = swz & 511;
    const int h = rem >> 5;
    const int r0 = (rem & 31) * 128;

    const unsigned short* lat = z ? lat_v : lat_k;
    const unsigned short* WT  = z ? WvrT : WkrT;
    const float* bias = z ? bvr : bkr;

    const int tid = threadIdx.x;
    const int lane = tid & 63, wid = tid >> 6;
    const int lr = lane & 15, lg = lane >> 4;
    const int wm = wid >> 1, wn = wid & 1;

    #pragma unroll
    for (int c = 0; c < 4; ++c) {
        int e = c * 256 + tid;
        int row = e >> 3, pc = e & 7;
        gload16(lat + (size_t)(r0 + row) * 1024 + h * 64 + ((pc ^ (row & 7)) * 8),
                Alds + e * 8);
    }
    #pragma unroll
    for (int c = 0; c < 4; ++c) {
        int e = c * 256 + tid;
        int d = e >> 3, pc = e & 7;
        gload16(WT + (size_t)d * 64 + ((pc ^ (d & 7)) * 8), Blds + e * 8);
    }
    __syncthreads();

    f32x4 acc[4][4];
    #pragma unroll
    for (int m = 0; m < 4; ++m)
        #pragma unroll
        for (int n = 0; n < 4; ++n) acc[m][n] = (f32x4){0.f, 0.f, 0.f, 0.f};

    #pragma unroll
    for (int ks = 0; ks < 2; ++ks) {
        bf16x8 af[4], bfv[4];
        #pragma unroll
        for (int m = 0; m < 4; ++m) {
            int row = wm * 64 + m * 16 + lr;
            af[m] = *(const bf16x8*)&Alds[row * 64 + (((ks * 4 + lg) ^ (row & 7)) * 8)];
        }
        #pragma unroll
        for (int n = 0; n < 4; ++n) {
            int row = wn * 64 + n * 16 + lr;
            bfv[n] = *(const bf16x8*)&Blds[row * 64 + (((ks * 4 + lg) ^ (row & 7)) * 8)];
        }
        #pragma unroll
        for (int m = 0; m < 4; ++m)
            #pragma unroll
            for (int n = 0; n < 4; ++n)
                acc[m][n] = __builtin_amdgcn_mfma_f32_16x16x32_bf16(af[m], bfv[n], acc[m][n], 0, 0, 0);
    }

    const int b = r0 >> 11;
    float bv[4];
    #pragma unroll
    for (int n = 0; n < 4; ++n) bv[n] = bias[wn * 64 + n * 16 + lr];

    #pragma unroll
    for (int m = 0; m < 4; ++m) {
        #pragma unroll
        for (int n = 0; n < 4; ++n) {
            const int d = wn * 64 + n * 16 + lr;
            const int rowb = r0 + wm * 64 + m * 16 + lg * 4;
            if (z == 0) {
                #pragma unroll
                for (int j = 0; j < 4; ++j)
                    k_bf[(size_t)(rowb + j) * D_MODEL + h * D_HEAD + d] =
                        f2bf(acc[m][n][j] + bv[n]);
            } else {
                us4v o = { f2bf(acc[m][n][0] + bv[n]), f2bf(acc[m][n][1] + bv[n]),
                           f2bf(acc[m][n][2] + bv[n]), f2bf(acc[m][n][3] + bv[n]) };
                *(us4v*)&v_t[((size_t)(b * 16 + h) * 128 + d) * 2048 + (rowb & 2047)] = o;
            }
        }
    }
}

// ---------------------------------------------------------------------------
// Causal flash attention — monolithic gated version (proven, R11).
// ---------------------------------------------------------------------------
static __device__ __forceinline__ void flash_stage(
    const unsigned short* __restrict__ kgh,
    const unsigned short* __restrict__ vtb,
    unsigned short* Kl, unsigned short* Vl, int kv0, int tid)
{
    #pragma unroll
    for (int c = 0; c < 4; ++c) {
        int idx = c * 256 + tid;
        int r = idx >> 4, ch = idx & 15;
        gload16(kgh + (size_t)(kv0 + r) * D_MODEL + ((ch ^ (r & 7)) * 8), Kl + idx * 8);
    }
    #pragma unroll
    for (int c = 0; c < 4; ++c) {
        int idx = c * 256 + tid;
        int d = idx >> 3, ch = idx & 7;
        gload16(vtb + (size_t)d * S_LEN + kv0 + ((ch ^ (d & 7)) * 8), Vl + idx * 8);
    }
}

__global__ __launch_bounds__(256, 2) void flash_kernel(
    const unsigned short* __restrict__ Q,
    const unsigned short* __restrict__ Kg,
    const unsigned short* __restrict__ Vt,
    unsigned short* __restrict__ Og)
{
    __shared__ unsigned short Klds[2][64 * 128];
    __shared__ unsigned short Vlds[2][128 * 64];

    const int tid = threadIdx.x;
    const int lane = tid & 63, wid = tid >> 6;
    const int lc = lane & 31, hi = lane >> 5;

    const int blk = blockIdx.x;
    const int jj = blk >> 5;
    const int qt = (jj < 8) ? (15 - jj) : (jj - 8);   // heavy first
    const int bh = blk & 31;
    const int b = bh >> 4, h = bh & 15;
    const size_t base = (size_t)b * S_LEN * D_MODEL;
    const unsigned short* kgh = Kg + base + h * D_HEAD;
    const unsigned short* vtb = Vt + (size_t)bh * D_HEAD * S_LEN;

    const int q0w = qt * 128 + wid * 32;
    const int qcol = q0w + lc;

    bf16x8 qf[8];
    #pragma unroll
    for (int dc = 0; dc < 8; ++dc)
        qf[dc] = *(const bf16x8*)&Q[base + (size_t)qcol * D_MODEL + h * D_HEAD + dc * 16 + hi * 8];

    f32x16 o_acc[4];
    #pragma unroll
    for (int dt = 0; dt < 4; ++dt)
        #pragma unroll
        for (int r = 0; r < 16; ++r) o_acc[dt][r] = 0.f;
    float m_r = -3e38f, l_r = 0.f;

    const int kxor = lc & 7;
    const int nt = 2 * qt + 2;

    int koff[16];
    #pragma unroll
    for (int dc = 0; dc < 8; ++dc) {
        koff[2 * dc]     = lc * 128 + (((dc * 2 + hi) ^ kxor) * 8);
        koff[2 * dc + 1] = (32 + lc) * 128 + (((dc * 2 + hi) ^ kxor) * 8);
    }

    flash_stage(kgh, vtb, Klds[0], Vlds[0], 0, tid);

    #pragma unroll 1
    for (int t = 0; t < nt; ++t) {
        const int bb = t & 1;
        const int kv0 = t * 64;

        asm volatile("s_waitcnt vmcnt(0)" ::: "memory");
        __builtin_amdgcn_s_barrier();
        asm volatile("" ::: "memory");

        if (t + 1 < nt)
            flash_stage(kgh, vtb, Klds[bb ^ 1], Vlds[bb ^ 1], (t + 1) * 64, tid);

        const unsigned short* Kb = Klds[bb];
        const unsigned short* Vb = Vlds[bb];

        f32x16 s0a, s0b, s1a, s1b;
        #pragma unroll
        for (int r = 0; r < 16; ++r) { s0a[r] = 0.f; s0b[r] = 0.f; s1a[r] = 0.f; s1b[r] = 0.f; }

        bf16x8 kf[8];
        #pragma unroll
        for (int i = 0; i < 8; ++i) kf[i] = ds_read128(&Kb[koff[i]]);
        asm volatile("s_waitcnt lgkmcnt(0)" ::: "memory");
        __builtin_amdgcn_sched_barrier(0);
        __builtin_amdgcn_s_setprio(1);
        #pragma unroll
        for (int dc = 0; dc < 4; ++dc) {
            s0a = __builtin_amdgcn_mfma_f32_32x32x16_bf16(kf[2 * dc],     qf[dc], s0a, 0, 0, 0);
            s1a = __builtin_amdgcn_mfma_f32_32x32x16_bf16(kf[2 * dc + 1], qf[dc], s1a, 0, 0, 0);
        }
        __builtin_amdgcn_s_setprio(0);

        #pragma unroll
        for (int i = 0; i < 8; ++i) kf[i] = ds_read128(&Kb[koff[8 + i]]);
        asm volatile("s_waitcnt lgkmcnt(0)" ::: "memory");
        __builtin_amdgcn_sched_barrier(0);
        __builtin_amdgcn_s_setprio(1);
        #pragma unroll
        for (int dc = 0; dc < 4; ++dc) {
            s0b = __builtin_amdgcn_mfma_f32_32x32x16_bf16(kf[2 * dc],     qf[dc + 4], s0b, 0, 0, 0);
            s1b = __builtin_amdgcn_mfma_f32_32x32x16_bf16(kf[2 * dc + 1], qf[dc + 4], s1b, 0, 0, 0);
        }
        __builtin_amdgcn_s_setprio(0);

        f32x16 s0 = s0a + s0b;
        f32x16 s1 = s1a + s1b;

        if (t >= nt - 2) {
            #pragma unroll
            for (int r = 0; r < 16; ++r) {
                int krow = (r & 3) + 8 * (r >> 2) + 4 * hi;
                if (kv0 + krow > qcol)      s0[r] = -3e38f;
                if (kv0 + 32 + krow > qcol) s1[r] = -3e38f;
            }
        }

        float mt[8];
        #pragma unroll
        for (int i = 0; i < 8; ++i)
            mt[i] = fmaxf(fmaxf(s0[2 * i], s0[2 * i + 1]), fmaxf(s1[2 * i], s1[2 * i + 1]));
        float mA = fmaxf(fmaxf(mt[0], mt[1]), fmaxf(mt[2], mt[3]));
        float mB = fmaxf(fmaxf(mt[4], mt[5]), fmaxf(mt[6], mt[7]));
        float sm = fmaxf(mA, mB);
        sm = fmaxf(sm, __shfl_xor(sm, 32));

        if (__any(sm > m_r + 11.5f)) {
            float mnew = fmaxf(m_r, sm);
            float alpha = exp2_hw(m_r - mnew);
            l_r *= alpha;
            m_r = mnew;
            #pragma unroll
            for (int r = 0; r < 16; ++r) {
                float av = __shfl(alpha, (r & 3) + 8 * (r >> 2) + 4 * hi);
                #pragma unroll
                for (int dt = 0; dt < 4; ++dt) o_acc[dt][r] *= av;
            }
        }

        #pragma unroll
        for (int r = 0; r < 16; ++r) {
            s0[r] = exp2_hw(s0[r] - m_r);
            s1[r] = exp2_hw(s1[r] - m_r);
        }
        float st[8];
        #pragma unroll
        for (int i = 0; i < 8; ++i)
            st[i] = (s0[2 * i] + s0[2 * i + 1]) + (s1[2 * i] + s1[2 * i + 1]);
        l_r += ((st[0] + st[1]) + (st[2] + st[3])) + ((st[4] + st[5]) + (st[6] + st[7]));

        #pragma unroll
        for (int t32 = 0; t32 < 2; ++t32) {
            const f32x16& s = t32 ? s1 : s0;
            unsigned int c0[4], c1[4];
            #pragma unroll
            for (int g = 0; g < 4; ++g) {
                c0[g] = cvtpk_bf16(s[4 * g],     s[4 * g + 1]);
                c1[g] = cvtpk_bf16(s[4 * g + 2], s[4 * g + 3]);
            }
            bf16x8 pf[2];
            #pragma unroll
            for (int kt = 0; kt < 2; ++kt) {
                unsigned int sel0 = hi ? c0[2 * kt] : c0[2 * kt + 1];
                unsigned int sel1 = hi ? c1[2 * kt] : c1[2 * kt + 1];
                unsigned int o0 = (unsigned int)__shfl_xor((int)sel0, 32);
                unsigned int o1 = (unsigned int)__shfl_xor((int)sel1, 32);
                u32x4 uu;
                uu.x = hi ? o0 : c0[2 * kt];
                uu.y = hi ? o1 : c1[2 * kt];
                uu.z = hi ? c0[2 * kt + 1] : o0;
                uu.w = hi ? c1[2 * kt + 1] : o1;
                pf[kt] = __builtin_bit_cast(bf16x8, uu);
            }
            bf16x8 vf[8];
            #pragma unroll
            for (int kt = 0; kt < 2; ++kt)
                #pragma unroll
                for (int dt = 0; dt < 4; ++dt)
                    vf[kt * 4 + dt] = ds_read128(
                        &Vb[(dt * 32 + lc) * 64 + (((t32 * 4 + kt * 2 + hi) ^ kxor) * 8)]);
            asm volatile("s_waitcnt lgkmcnt(0)" ::: "memory");
            __builtin_amdgcn_sched_barrier(0);
            __builtin_amdgcn_s_setprio(1);
            #pragma unroll
            for (int kt = 0; kt < 2; ++kt)
                #pragma unroll
                for (int dt = 0; dt < 4; ++dt)
                    o_acc[dt] = __builtin_amdgcn_mfma_f32_32x32x16_bf16(
                        pf[kt], vf[kt * 4 + dt], o_acc[dt], 0, 0, 0);
            __builtin_amdgcn_s_setprio(0);
        }
    }

    float lt = l_r + __shfl_xor(l_r, 32);
    float inv = 1.0f / lt;
    #pragma unroll
    for (int r = 0; r < 16; ++r) {
        int qrow = (r & 3) + 8 * (r >> 2) + 4 * hi;
        float iv = __shfl(inv, qrow);
        #pragma unroll
        for (int dt = 0; dt < 4; ++dt)
            Og[base + (size_t)(q0w + qrow) * D_MODEL + h * D_HEAD + dt * 32 + lc] =
                f2bf(o_acc[dt][r] * iv);
    }
}

// ---------------------------------------------------------------------------
extern "C" void kernel_launch(void* const* d_in, const int* in_sizes, int n_in,
                              void* d_out, int out_size, void* d_ws, size_t ws_size,
                              hipStream_t stream)
{
    const float* queries = (const float*)d_in[0];
    const float* keys    = (const float*)d_in[1];
    const float* values  = (const float*)d_in[2];
    const float* Wq  = (const float*)d_in[3];
    const float* bq  = (const float*)d_in[4];
    const float* Wlk = (const float*)d_in[5];
    const float* blk = (const float*)d_in[6];
    const float* Wlv = (const float*)d_in[7];
    const float* blv = (const float*)d_in[8];
    const float* Wkr = (const float*)d_in[9];
    const float* bkr = (const float*)d_in[10];
    const float* Wvr = (const float*)d_in[11];
    const float* bvr = (const float*)d_in[12];
    const float* Wo  = (const float*)d_in[13];
    const float* bo  = (const float*)d_in[14];
    float* out = (float*)d_out;

    char* ws = (char*)d_ws;
    const size_t MB = 1024 * 1024;
    unsigned short* abf_q = (unsigned short*)(ws);            // 16MB; ao aliases
    unsigned short* abf_k = (unsigned short*)(ws + 16 * MB);  // 16MB
    unsigned short* abf_v = (unsigned short*)(ws + 32 * MB);
    unsigned short* q_bf  = (unsigned short*)(ws + 48 * MB);
    unsigned short* k_bf  = (unsigned short*)(ws + 64 * MB);
    unsigned short* v_t   = (unsigned short*)(ws + 80 * MB);
    unsigned short* lat_k = (unsigned short*)(ws + 96 * MB);   // 8MB
    unsigned short* lat_v = (unsigned short*)(ws + 104 * MB);  // 8MB
    unsigned short* WqT   = (unsigned short*)(ws + 112 * MB);  // 8MB
    unsigned short* WlkT  = (unsigned short*)(ws + 120 * MB);  // 4MB
    unsigned short* WlvT  = (unsigned short*)(ws + 124 * MB);  // 4MB
    unsigned short* WkrT  = (unsigned short*)(ws + 128 * MB);  // 16KB
    unsigned short* WvrT  = WkrT + 128 * 64;
    unsigned short* WoT   = (unsigned short*)(ws + 129 * MB);  // 8MB
    unsigned short* ao    = abf_q;   // dead after stage1

    prep_kernel<<<16385, 256, 0, stream>>>(
        queries, keys, values, Wq, Wlk, Wlv, Wo, Wkr, Wvr,
        abf_q, abf_k, abf_v, WqT, WlkT, WlvT, WoT, WkrT, WvrT);

    stage1_8p_kernel<<<256, 512, 0, stream>>>(
        abf_q, abf_k, abf_v, WqT, WlkT, WlvT, bq, blk, blv,
        q_bf, lat_k, lat_v);

    recon_kernel<<<1024, 256, 0, stream>>>(
        lat_k, lat_v, WkrT, WvrT, bkr, bvr, k_bf, v_t);

    flash_kernel<<<512, 256, 0, stream>>>(q_bf, k_bf, v_t, ao);

    out_gemm8p_kernel<<<256, 512, 0, stream>>>(ao, WoT, bo, out);
}